// Round 6
// baseline (524.514 us; speedup 1.0000x reference)
//
#include <hip/hip_runtime.h>

// Capsule routing: B=32, N_IN=2048, IN_DIM=32, N_OUT=64, OUT_DIM=32, 3 iterations.
#define NI   2048
#define NO   64
#define DD   32
#define ODIM 2048   // NO*DD, the fused (o,d) axis

typedef short bf16x8 __attribute__((ext_vector_type(8)));
typedef float f32x4  __attribute__((ext_vector_type(4)));
typedef unsigned int u32x2 __attribute__((ext_vector_type(2)));
typedef unsigned int u32x4 __attribute__((ext_vector_type(4)));

__device__ __forceinline__ unsigned int cvt_pk_bf16(float lo, float hi) {
  unsigned int r;
  asm("v_cvt_pk_bf16_f32 %0, %1, %2" : "=v"(r) : "v"(lo), "v"(hi));
  return r;
}
__device__ __forceinline__ float bflo(unsigned int u) { return __uint_as_float(u << 16); }
__device__ __forceinline__ float bfhi(unsigned int u) { return __uint_as_float(u & 0xffff0000u); }

union BFPack { unsigned int u[4]; bf16x8 v; };

// K1: u_hat[b][i][od] (bf16) = sum_k W[o,i,d,k]*x[b,i,k], via MFMA 16x16x32 bf16.
// Structure = R4 (verified passing) with ONE change: W loads for 4 i's are
// batch-issued (8 NT f32x4 back-to-back) before consumption, so each wave keeps
// ~8KB of HBM reads in flight instead of 1 serial load->cvt->MFMA chain
// (R3/R4 showed VGPR=32, VALUBusy 2.5%, latency-bound at ~330us vs 130us floor).
// __launch_bounds__(256,4) gives the allocator room (<=128 VGPR).
// MFMA outputs go via LDS tile [8i][32b][64od] -> cooperative full-line NT stores.
// Also accumulates per-(ib) partial sums over i (iter-1 s, c==1/64 uniform).
__global__ __launch_bounds__(256, 4) void k1_uhat(
    const float* __restrict__ W, const float* __restrict__ X,
    unsigned short* __restrict__ U, float* __restrict__ part) {
  __shared__ __attribute__((aligned(16))) char lds[8 * 32 * 144];  // 36,864 B
  const int tid   = threadIdx.x;
  const int lane  = tid & 63;
  const int w     = tid >> 6;
  const int ob    = blockIdx.x & 31;   // 64-od block
  const int ib    = blockIdx.x >> 5;   // i-block of 32
  const int odq   = (ob << 2) + w;     // 16-od strip
  const int o     = odq >> 1;          // output capsule
  const int db    = (odq & 1) << 4;    // d base within o
  const int row16 = lane & 15;         // A row within 16
  const int kg    = lane >> 4;         // k-group
  const int k0    = kg << 3;           // k offset (8 contiguous)
  const int crow  = kg << 2;           // C/D row base [m89 verified]
  const int ccol  = lane & 15;         // C/D col

  f32x4 sacc[2];
  sacc[0] = f32x4{0.f, 0.f, 0.f, 0.f};
  sacc[1] = f32x4{0.f, 0.f, 0.f, 0.f};

  const float* wbase = W + (((size_t)o * NI) << 10) + ((db + row16) << 5) + k0;
  const int odl = (w << 4) + crow;     // od within the 64-od block (lane-const)

  for (int p = 0; p < 4; ++p) {
    const int i0 = (ib << 5) + (p << 3);
#pragma unroll
    for (int h = 0; h < 2; ++h) {
      const int ia = i0 + (h << 2);
      // ---- batch-issue W loads for 4 i's (8 NT dwordx4 in flight) ----
      f32x4 wa[4], wb[4];
#pragma unroll
      for (int j = 0; j < 4; ++j) {
        const f32x4* wp = (const f32x4*)(wbase + ((size_t)(ia + j) << 10));
        wa[j] = __builtin_nontemporal_load(wp);
        wb[j] = __builtin_nontemporal_load(wp + 1);
      }
      // ---- consume: per i, X fragments (L2-warm fp32) + cvt + 2 MFMA ----
#pragma unroll
      for (int j = 0; j < 4; ++j) {
        const int i  = ia + j;
        const int ii = (h << 2) + j;
        bf16x8 bfrag[2];
#pragma unroll
        for (int bt = 0; bt < 2; ++bt) {
          const int bcol = ccol + (bt << 4);
          const float* xp = X + (((size_t)(bcol * NI + i)) << 5) + k0;
          const float4 x0 = *(const float4*)xp;
          const float4 x1 = *(const float4*)(xp + 4);
          BFPack t;
          t.u[0] = cvt_pk_bf16(x0.x, x0.y);
          t.u[1] = cvt_pk_bf16(x0.z, x0.w);
          t.u[2] = cvt_pk_bf16(x1.x, x1.y);
          t.u[3] = cvt_pk_bf16(x1.z, x1.w);
          bfrag[bt] = t.v;
        }
        BFPack af;
        af.u[0] = cvt_pk_bf16(wa[j].x, wa[j].y);
        af.u[1] = cvt_pk_bf16(wa[j].z, wa[j].w);
        af.u[2] = cvt_pk_bf16(wb[j].x, wb[j].y);
        af.u[3] = cvt_pk_bf16(wb[j].z, wb[j].w);
#pragma unroll
        for (int bt = 0; bt < 2; ++bt) {
          f32x4 d = __builtin_amdgcn_mfma_f32_16x16x32_bf16(
              af.v, bfrag[bt], f32x4{0.f, 0.f, 0.f, 0.f}, 0, 0, 0);
          sacc[bt] += d;
          const int b = ccol + (bt << 4);
          u32x2 pk;
          pk.x = cvt_pk_bf16(d[0], d[1]);
          pk.y = cvt_pk_bf16(d[2], d[3]);
          *(u32x2*)(lds + ((ii << 5) + b) * 144 + (odl << 1)) = pk;
        }
      }
    }
    __syncthreads();
    // Cooperative write-out: thread t covers 16B of u[b][i0+r][ob*64+od16*8..+8];
    // 8 consecutive threads = 128B contiguous -> full 64B lines -> NT-safe.
    {
      const int b    = tid >> 3;
      const int od16 = tid & 7;
#pragma unroll
      for (int r = 0; r < 8; ++r) {
        const u32x4 v = *(const u32x4*)(lds + ((r << 5) + b) * 144 + (od16 << 4));
        const size_t goff = (((size_t)(b * NI + i0 + r)) << 11) + (ob << 6) + (od16 << 3);
        __builtin_nontemporal_store(v, (u32x4*)(U + goff));
      }
    }
    __syncthreads();
  }

  // per-i-block partial sums: part[ib][b][od] (wave-exclusive slice)
#pragma unroll
  for (int bt = 0; bt < 2; ++bt) {
    const int b  = ccol + (bt << 4);
    const int od = (ob << 6) + odl;
    float* pp = part + (((size_t)((ib << 5) + b)) << 11) + od;
    float4 t; t.x = sacc[bt][0]; t.y = sacc[bt][1];
    t.z = sacc[bt][2]; t.w = sacc[bt][3];
    *(float4*)pp = t;
  }
}

// Reduce partials over 64 chunks -> s[b,o,:], squash -> vout[b][o][d].
// wave <-> (b,o). 2048 waves = 512 blocks. scale: 1/64 for iter 1 (uniform c), else 1.
__global__ __launch_bounds__(256) void k_reduce(
    const float* __restrict__ part, float* __restrict__ vout, float scale) {
  const int tid  = threadIdx.x;
  const int lane = tid & 63;
  const int wid  = (blockIdx.x << 2) + (tid >> 6);
  const int o = wid & 63, b = wid >> 6;
  const int d = lane & 31, h = lane >> 5;
  float s = 0.f;
  for (int c = h; c < 64; c += 2)
    s += part[(((size_t)((c << 5) + b)) << 11) + (o << 5) + d];
  s += __shfl_xor(s, 32);
  s *= scale;
  float p = s * s;
#pragma unroll
  for (int off = 1; off < 32; off <<= 1) p += __shfl_xor(p, off);
  const float v = (p > 0.f) ? s * sqrtf(p) / (1.f + p) : 0.f;
  if (h == 0) vout[(((b << 6) + o) << 5) + d] = v;
}

// Routing pass: per (b,i): logits[o] = sum_d u*(v1[+v2]); softmax over o (64 lanes);
// partial s accumulation in registers; per-block LDS combine -> part[chunk][b][od].
// block <-> (b, chunk of 32 i); 4 waves x 8 i each. lane <-> o.
__global__ __launch_bounds__(256) void k_route(
    const unsigned short* __restrict__ U, const float* __restrict__ V1,
    const float* __restrict__ V2, float* __restrict__ part) {
  __shared__ float red[4][ODIM];   // 32 KiB
  const int tid   = threadIdx.x;
  const int lane  = tid & 63;
  const int w     = tid >> 6;
  const int b     = blockIdx.x >> 6;
  const int chunk = blockIdx.x & 63;
  const int o     = lane;

  // v (or v1+v2) for this lane's o: 32 regs, reused across all i
  float vs[32];
  {
    const float* vp = V1 + (((b << 6) + o) << 5);
#pragma unroll
    for (int j = 0; j < 8; ++j) {
      const float4 t = *(const float4*)(vp + (j << 2));
      vs[4*j+0] = t.x; vs[4*j+1] = t.y; vs[4*j+2] = t.z; vs[4*j+3] = t.w;
    }
    if (V2 != nullptr) {
      const float* vq = V2 + (((b << 6) + o) << 5);
#pragma unroll
      for (int j = 0; j < 8; ++j) {
        const float4 t = *(const float4*)(vq + (j << 2));
        vs[4*j+0] += t.x; vs[4*j+1] += t.y; vs[4*j+2] += t.z; vs[4*j+3] += t.w;
      }
    }
  }

  float pacc[32];
#pragma unroll
  for (int d = 0; d < 32; ++d) pacc[d] = 0.f;

  const int i0 = (chunk << 5) + (w << 3);
  const unsigned short* ub = U + (((size_t)b * NI) << 11);

  u32x4 q0, q1, q2, q3;   // prefetched 64B u-row slice for this lane's o
  {
    const u32x4* p = (const u32x4*)(ub + (((size_t)i0) << 11) + (o << 5));
    q0 = __builtin_nontemporal_load(p);
    q1 = __builtin_nontemporal_load(p + 1);
    q2 = __builtin_nontemporal_load(p + 2);
    q3 = __builtin_nontemporal_load(p + 3);
  }
  for (int ii = 0; ii < 8; ++ii) {
    const u32x4 c0 = q0, c1 = q1, c2 = q2, c3 = q3;
    if (ii < 7) {
      const u32x4* p = (const u32x4*)(ub + (((size_t)(i0 + ii + 1)) << 11) + (o << 5));
      q0 = __builtin_nontemporal_load(p);
      q1 = __builtin_nontemporal_load(p + 1);
      q2 = __builtin_nontemporal_load(p + 2);
      q3 = __builtin_nontemporal_load(p + 3);
    }
    float uf[32];
    uf[ 0]=bflo(c0.x); uf[ 1]=bfhi(c0.x); uf[ 2]=bflo(c0.y); uf[ 3]=bfhi(c0.y);
    uf[ 4]=bflo(c0.z); uf[ 5]=bfhi(c0.z); uf[ 6]=bflo(c0.w); uf[ 7]=bfhi(c0.w);
    uf[ 8]=bflo(c1.x); uf[ 9]=bfhi(c1.x); uf[10]=bflo(c1.y); uf[11]=bfhi(c1.y);
    uf[12]=bflo(c1.z); uf[13]=bfhi(c1.z); uf[14]=bflo(c1.w); uf[15]=bfhi(c1.w);
    uf[16]=bflo(c2.x); uf[17]=bfhi(c2.x); uf[18]=bflo(c2.y); uf[19]=bfhi(c2.y);
    uf[20]=bflo(c2.z); uf[21]=bfhi(c2.z); uf[22]=bflo(c2.w); uf[23]=bfhi(c2.w);
    uf[24]=bflo(c3.x); uf[25]=bfhi(c3.x); uf[26]=bflo(c3.y); uf[27]=bfhi(c3.y);
    uf[28]=bflo(c3.z); uf[29]=bfhi(c3.z); uf[30]=bflo(c3.w); uf[31]=bfhi(c3.w);

    float dotA = 0.f, dotB = 0.f;
#pragma unroll
    for (int d = 0; d < 16; ++d) {
      dotA = fmaf(uf[d], vs[d], dotA);
      dotB = fmaf(uf[d + 16], vs[d + 16], dotB);
    }
    const float dot = dotA + dotB;
    float m = dot;
#pragma unroll
    for (int off = 1; off < 64; off <<= 1) m = fmaxf(m, __shfl_xor(m, off));
    const float e = __expf(dot - m);
    float Z = e;
#pragma unroll
    for (int off = 1; off < 64; off <<= 1) Z += __shfl_xor(Z, off);
    const float c = e / Z;
#pragma unroll
    for (int d = 0; d < 32; ++d) pacc[d] = fmaf(c, uf[d], pacc[d]);
  }

#pragma unroll
  for (int j = 0; j < 8; ++j) {
    float4 t; t.x = pacc[4*j]; t.y = pacc[4*j+1]; t.z = pacc[4*j+2]; t.w = pacc[4*j+3];
    *(float4*)&red[w][(o << 5) + (j << 2)] = t;
  }
  __syncthreads();
  float* pout = part + (((size_t)((chunk << 5) + b)) << 11);
  for (int t = tid; t < ODIM; t += 256)
    pout[t] = red[0][t] + red[1][t] + red[2][t] + red[3][t];
}

extern "C" void kernel_launch(void* const* d_in, const int* in_sizes, int n_in,
                              void* d_out, int out_size, void* d_ws, size_t ws_size,
                              hipStream_t stream) {
  const float* X = (const float*)d_in[0];   // [32][2048][32]
  const float* W = (const float*)d_in[1];   // [64][2048][32][32]
  float* out = (float*)d_out;               // [32][64][32]
  char* ws = (char*)d_ws;

  // ws layout: u_hat bf16 256MiB | part fp32 16MiB | v1 | v2   (~272.5 MiB)
  unsigned short* U = (unsigned short*)ws;
  float* part = (float*)(ws + ((size_t)268435456));
  float* v1   = (float*)(ws + ((size_t)268435456 + 16777216));
  float* v2   = v1 + 65536;

  // iter 1: u_hat + uniform-c partial sums fused
  k1_uhat<<<2048, 256, 0, stream>>>(W, X, U, part);
  k_reduce<<<512, 256, 0, stream>>>(part, v1, 1.f / 64.f);
  // iter 2: logits = u.v1
  k_route<<<2048, 256, 0, stream>>>(U, v1, nullptr, part);
  k_reduce<<<512, 256, 0, stream>>>(part, v2, 1.f);
  // iter 3: logits = u.v1 + u.v2 = u.(v1+v2)
  k_route<<<2048, 256, 0, stream>>>(U, v1, v2, part);
  k_reduce<<<512, 256, 0, stream>>>(part, out, 1.f);
}

// Round 7
// 460.357 us; speedup vs baseline: 1.1394x; 1.1394x over previous
//
#include <hip/hip_runtime.h>

// Capsule routing: B=32, N_IN=2048, IN_DIM=32, N_OUT=64, OUT_DIM=32, 3 iterations.
#define NI   2048
#define NO   64
#define DD   32
#define ODIM 2048   // NO*DD, the fused (o,d) axis

typedef short bf16x8 __attribute__((ext_vector_type(8)));
typedef float f32x4  __attribute__((ext_vector_type(4)));
typedef unsigned int u32x2 __attribute__((ext_vector_type(2)));
typedef unsigned int u32x4 __attribute__((ext_vector_type(4)));

__device__ __forceinline__ unsigned int cvt_pk_bf16(float lo, float hi) {
  unsigned int r;
  asm("v_cvt_pk_bf16_f32 %0, %1, %2" : "=v"(r) : "v"(lo), "v"(hi));
  return r;
}
__device__ __forceinline__ float bflo(unsigned int u) { return __uint_as_float(u << 16); }
__device__ __forceinline__ float bfhi(unsigned int u) { return __uint_as_float(u & 0xffff0000u); }

union BFPack { unsigned int u[4]; bf16x8 v; };

// K1: u_hat[b][i][od] (bf16) = sum_k W[o,i,d,k]*x[b,i,k], via MFMA 16x16x32 bf16.
// R7 = R6 with ONE change: plain __launch_bounds__(256) (R6's (256,4) is the
// only other delta vs the 467us R4 baseline and is suspect for the regression;
// occupancy is LDS-capped at 4 blocks/CU either way, so the min-waves contract
// only constrains the allocator/scheduler).
// Batched W loads stay: 8 NT f32x4 in flight per wave breaks the serial
// load->cvt->MFMA chain (R3: VGPR=32, VALUBusy 2.5%, latency-bound).
// MFMA outputs go via LDS tile [8i][32b][64od] -> cooperative full-line NT stores.
// Also accumulates per-(ib) partial sums over i (iter-1 s, c==1/64 uniform).
__global__ __launch_bounds__(256) void k1_uhat(
    const float* __restrict__ W, const float* __restrict__ X,
    unsigned short* __restrict__ U, float* __restrict__ part) {
  __shared__ __attribute__((aligned(16))) char lds[8 * 32 * 144];  // 36,864 B
  const int tid   = threadIdx.x;
  const int lane  = tid & 63;
  const int w     = tid >> 6;
  const int ob    = blockIdx.x & 31;   // 64-od block
  const int ib    = blockIdx.x >> 5;   // i-block of 32
  const int odq   = (ob << 2) + w;     // 16-od strip
  const int o     = odq >> 1;          // output capsule
  const int db    = (odq & 1) << 4;    // d base within o
  const int row16 = lane & 15;         // A row within 16
  const int kg    = lane >> 4;         // k-group
  const int k0    = kg << 3;           // k offset (8 contiguous)
  const int crow  = kg << 2;           // C/D row base [m89 verified]
  const int ccol  = lane & 15;         // C/D col

  f32x4 sacc[2];
  sacc[0] = f32x4{0.f, 0.f, 0.f, 0.f};
  sacc[1] = f32x4{0.f, 0.f, 0.f, 0.f};

  const float* wbase = W + (((size_t)o * NI) << 10) + ((db + row16) << 5) + k0;
  const int odl = (w << 4) + crow;     // od within the 64-od block (lane-const)

  for (int p = 0; p < 4; ++p) {
    const int i0 = (ib << 5) + (p << 3);
#pragma unroll
    for (int h = 0; h < 2; ++h) {
      const int ia = i0 + (h << 2);
      // ---- batch-issue W loads for 4 i's (8 NT dwordx4 in flight) ----
      f32x4 wa[4], wb[4];
#pragma unroll
      for (int j = 0; j < 4; ++j) {
        const f32x4* wp = (const f32x4*)(wbase + ((size_t)(ia + j) << 10));
        wa[j] = __builtin_nontemporal_load(wp);
        wb[j] = __builtin_nontemporal_load(wp + 1);
      }
      // ---- consume: per i, X fragments (L2-warm fp32) + cvt + 2 MFMA ----
#pragma unroll
      for (int j = 0; j < 4; ++j) {
        const int i  = ia + j;
        const int ii = (h << 2) + j;
        bf16x8 bfrag[2];
#pragma unroll
        for (int bt = 0; bt < 2; ++bt) {
          const int bcol = ccol + (bt << 4);
          const float* xp = X + (((size_t)(bcol * NI + i)) << 5) + k0;
          const float4 x0 = *(const float4*)xp;
          const float4 x1 = *(const float4*)(xp + 4);
          BFPack t;
          t.u[0] = cvt_pk_bf16(x0.x, x0.y);
          t.u[1] = cvt_pk_bf16(x0.z, x0.w);
          t.u[2] = cvt_pk_bf16(x1.x, x1.y);
          t.u[3] = cvt_pk_bf16(x1.z, x1.w);
          bfrag[bt] = t.v;
        }
        BFPack af;
        af.u[0] = cvt_pk_bf16(wa[j].x, wa[j].y);
        af.u[1] = cvt_pk_bf16(wa[j].z, wa[j].w);
        af.u[2] = cvt_pk_bf16(wb[j].x, wb[j].y);
        af.u[3] = cvt_pk_bf16(wb[j].z, wb[j].w);
#pragma unroll
        for (int bt = 0; bt < 2; ++bt) {
          f32x4 d = __builtin_amdgcn_mfma_f32_16x16x32_bf16(
              af.v, bfrag[bt], f32x4{0.f, 0.f, 0.f, 0.f}, 0, 0, 0);
          sacc[bt] += d;
          const int b = ccol + (bt << 4);
          u32x2 pk;
          pk.x = cvt_pk_bf16(d[0], d[1]);
          pk.y = cvt_pk_bf16(d[2], d[3]);
          *(u32x2*)(lds + ((ii << 5) + b) * 144 + (odl << 1)) = pk;
        }
      }
    }
    __syncthreads();
    // Cooperative write-out: thread t covers 16B of u[b][i0+r][ob*64+od16*8..+8];
    // 8 consecutive threads = 128B contiguous -> full 64B lines -> NT-safe.
    {
      const int b    = tid >> 3;
      const int od16 = tid & 7;
#pragma unroll
      for (int r = 0; r < 8; ++r) {
        const u32x4 v = *(const u32x4*)(lds + ((r << 5) + b) * 144 + (od16 << 4));
        const size_t goff = (((size_t)(b * NI + i0 + r)) << 11) + (ob << 6) + (od16 << 3);
        __builtin_nontemporal_store(v, (u32x4*)(U + goff));
      }
    }
    __syncthreads();
  }

  // per-i-block partial sums: part[ib][b][od] (wave-exclusive slice)
#pragma unroll
  for (int bt = 0; bt < 2; ++bt) {
    const int b  = ccol + (bt << 4);
    const int od = (ob << 6) + odl;
    float* pp = part + (((size_t)((ib << 5) + b)) << 11) + od;
    float4 t; t.x = sacc[bt][0]; t.y = sacc[bt][1];
    t.z = sacc[bt][2]; t.w = sacc[bt][3];
    *(float4*)pp = t;
  }
}

// Reduce partials over 64 chunks -> s[b,o,:], squash -> vout[b][o][d].
// wave <-> (b,o). 2048 waves = 512 blocks. scale: 1/64 for iter 1 (uniform c), else 1.
__global__ __launch_bounds__(256) void k_reduce(
    const float* __restrict__ part, float* __restrict__ vout, float scale) {
  const int tid  = threadIdx.x;
  const int lane = tid & 63;
  const int wid  = (blockIdx.x << 2) + (tid >> 6);
  const int o = wid & 63, b = wid >> 6;
  const int d = lane & 31, h = lane >> 5;
  float s = 0.f;
  for (int c = h; c < 64; c += 2)
    s += part[(((size_t)((c << 5) + b)) << 11) + (o << 5) + d];
  s += __shfl_xor(s, 32);
  s *= scale;
  float p = s * s;
#pragma unroll
  for (int off = 1; off < 32; off <<= 1) p += __shfl_xor(p, off);
  const float v = (p > 0.f) ? s * sqrtf(p) / (1.f + p) : 0.f;
  if (h == 0) vout[(((b << 6) + o) << 5) + d] = v;
}

// Routing pass: per (b,i): logits[o] = sum_d u*(v1[+v2]); softmax over o (64 lanes);
// partial s accumulation in registers; per-block LDS combine -> part[chunk][b][od].
// block <-> (b, chunk of 32 i); 4 waves x 8 i each. lane <-> o.
__global__ __launch_bounds__(256) void k_route(
    const unsigned short* __restrict__ U, const float* __restrict__ V1,
    const float* __restrict__ V2, float* __restrict__ part) {
  __shared__ float red[4][ODIM];   // 32 KiB
  const int tid   = threadIdx.x;
  const int lane  = tid & 63;
  const int w     = tid >> 6;
  const int b     = blockIdx.x >> 6;
  const int chunk = blockIdx.x & 63;
  const int o     = lane;

  // v (or v1+v2) for this lane's o: 32 regs, reused across all i
  float vs[32];
  {
    const float* vp = V1 + (((b << 6) + o) << 5);
#pragma unroll
    for (int j = 0; j < 8; ++j) {
      const float4 t = *(const float4*)(vp + (j << 2));
      vs[4*j+0] = t.x; vs[4*j+1] = t.y; vs[4*j+2] = t.z; vs[4*j+3] = t.w;
    }
    if (V2 != nullptr) {
      const float* vq = V2 + (((b << 6) + o) << 5);
#pragma unroll
      for (int j = 0; j < 8; ++j) {
        const float4 t = *(const float4*)(vq + (j << 2));
        vs[4*j+0] += t.x; vs[4*j+1] += t.y; vs[4*j+2] += t.z; vs[4*j+3] += t.w;
      }
    }
  }

  float pacc[32];
#pragma unroll
  for (int d = 0; d < 32; ++d) pacc[d] = 0.f;

  const int i0 = (chunk << 5) + (w << 3);
  const unsigned short* ub = U + (((size_t)b * NI) << 11);

  u32x4 q0, q1, q2, q3;   // prefetched 64B u-row slice for this lane's o
  {
    const u32x4* p = (const u32x4*)(ub + (((size_t)i0) << 11) + (o << 5));
    q0 = __builtin_nontemporal_load(p);
    q1 = __builtin_nontemporal_load(p + 1);
    q2 = __builtin_nontemporal_load(p + 2);
    q3 = __builtin_nontemporal_load(p + 3);
  }
  for (int ii = 0; ii < 8; ++ii) {
    const u32x4 c0 = q0, c1 = q1, c2 = q2, c3 = q3;
    if (ii < 7) {
      const u32x4* p = (const u32x4*)(ub + (((size_t)(i0 + ii + 1)) << 11) + (o << 5));
      q0 = __builtin_nontemporal_load(p);
      q1 = __builtin_nontemporal_load(p + 1);
      q2 = __builtin_nontemporal_load(p + 2);
      q3 = __builtin_nontemporal_load(p + 3);
    }
    float uf[32];
    uf[ 0]=bflo(c0.x); uf[ 1]=bfhi(c0.x); uf[ 2]=bflo(c0.y); uf[ 3]=bfhi(c0.y);
    uf[ 4]=bflo(c0.z); uf[ 5]=bfhi(c0.z); uf[ 6]=bflo(c0.w); uf[ 7]=bfhi(c0.w);
    uf[ 8]=bflo(c1.x); uf[ 9]=bfhi(c1.x); uf[10]=bflo(c1.y); uf[11]=bfhi(c1.y);
    uf[12]=bflo(c1.z); uf[13]=bfhi(c1.z); uf[14]=bflo(c1.w); uf[15]=bfhi(c1.w);
    uf[16]=bflo(c2.x); uf[17]=bfhi(c2.x); uf[18]=bflo(c2.y); uf[19]=bfhi(c2.y);
    uf[20]=bflo(c2.z); uf[21]=bfhi(c2.z); uf[22]=bflo(c2.w); uf[23]=bfhi(c2.w);
    uf[24]=bflo(c3.x); uf[25]=bfhi(c3.x); uf[26]=bflo(c3.y); uf[27]=bfhi(c3.y);
    uf[28]=bflo(c3.z); uf[29]=bfhi(c3.z); uf[30]=bflo(c3.w); uf[31]=bfhi(c3.w);

    float dotA = 0.f, dotB = 0.f;
#pragma unroll
    for (int d = 0; d < 16; ++d) {
      dotA = fmaf(uf[d], vs[d], dotA);
      dotB = fmaf(uf[d + 16], vs[d + 16], dotB);
    }
    const float dot = dotA + dotB;
    float m = dot;
#pragma unroll
    for (int off = 1; off < 64; off <<= 1) m = fmaxf(m, __shfl_xor(m, off));
    const float e = __expf(dot - m);
    float Z = e;
#pragma unroll
    for (int off = 1; off < 64; off <<= 1) Z += __shfl_xor(Z, off);
    const float c = e / Z;
#pragma unroll
    for (int d = 0; d < 32; ++d) pacc[d] = fmaf(c, uf[d], pacc[d]);
  }

#pragma unroll
  for (int j = 0; j < 8; ++j) {
    float4 t; t.x = pacc[4*j]; t.y = pacc[4*j+1]; t.z = pacc[4*j+2]; t.w = pacc[4*j+3];
    *(float4*)&red[w][(o << 5) + (j << 2)] = t;
  }
  __syncthreads();
  float* pout = part + (((size_t)((chunk << 5) + b)) << 11);
  for (int t = tid; t < ODIM; t += 256)
    pout[t] = red[0][t] + red[1][t] + red[2][t] + red[3][t];
}

extern "C" void kernel_launch(void* const* d_in, const int* in_sizes, int n_in,
                              void* d_out, int out_size, void* d_ws, size_t ws_size,
                              hipStream_t stream) {
  const float* X = (const float*)d_in[0];   // [32][2048][32]
  const float* W = (const float*)d_in[1];   // [64][2048][32][32]
  float* out = (float*)d_out;               // [32][64][32]
  char* ws = (char*)d_ws;

  // ws layout: u_hat bf16 256MiB | part fp32 16MiB | v1 | v2   (~272.5 MiB; ws=2GiB)
  unsigned short* U = (unsigned short*)ws;
  float* part = (float*)(ws + ((size_t)268435456));
  float* v1   = (float*)(ws + ((size_t)268435456 + 16777216));
  float* v2   = v1 + 65536;

  // iter 1: u_hat + uniform-c partial sums fused
  k1_uhat<<<2048, 256, 0, stream>>>(W, X, U, part);
  k_reduce<<<512, 256, 0, stream>>>(part, v1, 1.f / 64.f);
  // iter 2: logits = u.v1
  k_route<<<2048, 256, 0, stream>>>(U, v1, nullptr, part);
  k_reduce<<<512, 256, 0, stream>>>(part, v2, 1.f);
  // iter 3: logits = u.v1 + u.v2 = u.(v1+v2)
  k_route<<<2048, 256, 0, stream>>>(U, v1, v2, part);
  k_reduce<<<512, 256, 0, stream>>>(part, out, 1.f);
}

// Round 8
// 412.307 us; speedup vs baseline: 1.2721x; 1.1165x over previous
//
#include <hip/hip_runtime.h>

// Capsule routing: B=32, N_IN=2048, IN_DIM=32, N_OUT=64, OUT_DIM=32, 3 iterations.
#define NI   2048
#define NO   64
#define DD   32
#define ODIM 2048   // NO*DD, the fused (o,d) axis

typedef short bf16x8 __attribute__((ext_vector_type(8)));
typedef float f32x4  __attribute__((ext_vector_type(4)));
typedef unsigned int u32x2 __attribute__((ext_vector_type(2)));
typedef unsigned int u32x4 __attribute__((ext_vector_type(4)));

__device__ __forceinline__ unsigned int cvt_pk_bf16(float lo, float hi) {
  unsigned int r;
  asm("v_cvt_pk_bf16_f32 %0, %1, %2" : "=v"(r) : "v"(lo), "v"(hi));
  return r;
}
__device__ __forceinline__ float bflo(unsigned int u) { return __uint_as_float(u << 16); }
__device__ __forceinline__ float bfhi(unsigned int u) { return __uint_as_float(u & 0xffff0000u); }

union BFPack { unsigned int u[4]; bf16x8 v; };

// K1: u_hat[b][i][od] (bf16) = sum_k W[o,i,d,k]*x[b,i,k], via MFMA 16x16x32 bf16.
// R8 structural fix (k1 only): the consume loop's ONLY global ops are the W
// batch. X is staged per-8-i-phase into LDS (bf16, k-slot XOR swizzle), so
// consuming an i no longer FIFO-drains the W vmcnt queue (R4/R7 bottleneck
// theory: per-i X loads consumed immediately retire the whole W batch).
// W half-batches are issued one ahead (h+1 before consuming h; next phase's
// h0 before the barrier) and pinned with sched_barrier(0) so the compiler
// can't sink them to the use site. LDS 53,248B -> 3 blocks/CU = 12 waves/CU.
__global__ __launch_bounds__(256) void k1_uhat(
    const float* __restrict__ W, const float* __restrict__ X,
    unsigned short* __restrict__ U, float* __restrict__ part) {
  __shared__ __attribute__((aligned(16))) char olds[8 * 32 * 144];        // 36,864 B
  __shared__ __attribute__((aligned(16))) unsigned short xlds[8][32][32]; // 16,384 B
  const int tid   = threadIdx.x;
  const int lane  = tid & 63;
  const int w     = tid >> 6;
  const int ob    = blockIdx.x & 31;   // 64-od block
  const int ib    = blockIdx.x >> 5;   // i-block of 32
  const int odq   = (ob << 2) + w;     // 16-od strip
  const int o     = odq >> 1;          // output capsule
  const int db    = (odq & 1) << 4;    // d base within o
  const int row16 = lane & 15;         // A row within 16
  const int kg    = lane >> 4;         // k-group
  const int k0    = kg << 3;           // k offset (8 contiguous)
  const int crow  = kg << 2;           // C/D row base [m89 verified]
  const int ccol  = lane & 15;         // C/D col
  const int odl   = (w << 4) + crow;   // od within 64-od block
  const int sb    = tid >> 3;          // stage: b (0..31)
  const int sii   = tid & 7;           // stage: i within phase (0..7)
  const int xslot = (kg ^ (ccol & 3)) << 3;  // swizzled k-slot for consume reads

  f32x4 sacc[2];
  sacc[0] = f32x4{0.f, 0.f, 0.f, 0.f};
  sacc[1] = f32x4{0.f, 0.f, 0.f, 0.f};

  const float* wbase = W + (((size_t)o * NI) << 10) + ((db + row16) << 5) + k0;

  // Stage X[all b][phase 8 i][all k] -> xlds bf16. One (b,i) row per thread:
  // 8 coalesced float4 loads, cvt, 4 swizzled b128 LDS writes.
  auto STAGE = [&](int p) {
    const int i = (ib << 5) + (p << 3) + sii;
    const float4* xp = (const float4*)(X + (((size_t)(sb * NI + i)) << 5));
    float4 xv[8];
#pragma unroll
    for (int j = 0; j < 8; ++j) xv[j] = xp[j];
#pragma unroll
    for (int j = 0; j < 4; ++j) {
      u32x4 pk;
      pk.x = cvt_pk_bf16(xv[2*j].x,   xv[2*j].y);
      pk.y = cvt_pk_bf16(xv[2*j].z,   xv[2*j].w);
      pk.z = cvt_pk_bf16(xv[2*j+1].x, xv[2*j+1].y);
      pk.w = cvt_pk_bf16(xv[2*j+1].z, xv[2*j+1].w);
      *(u32x4*)&xlds[sii][sb][(j ^ (sb & 3)) << 3] = pk;
    }
  };

  // Issue W NT loads for a 4-i half-batch; pin the issue point.
  auto ISSUE = [&](int p, int h, f32x4* wa, f32x4* wb) {
    const int ia = (ib << 5) + (p << 3) + (h << 2);
#pragma unroll
    for (int j = 0; j < 4; ++j) {
      const f32x4* wp = (const f32x4*)(wbase + ((size_t)(ia + j) << 10));
      wa[j] = __builtin_nontemporal_load(wp);
      wb[j] = __builtin_nontemporal_load(wp + 1);
    }
    __builtin_amdgcn_sched_barrier(0);
  };

  // Consume a staged half-batch: A from W regs, B from xlds, 2 MFMA -> olds.
  auto CONSUME = [&](int h, const f32x4* wa, const f32x4* wb) {
#pragma unroll
    for (int j = 0; j < 4; ++j) {
      const int ii = (h << 2) + j;
      bf16x8 bx0 = *(const bf16x8*)&xlds[ii][ccol][xslot];
      bf16x8 bx1 = *(const bf16x8*)&xlds[ii][ccol + 16][xslot];
      BFPack af;
      af.u[0] = cvt_pk_bf16(wa[j].x, wa[j].y);
      af.u[1] = cvt_pk_bf16(wa[j].z, wa[j].w);
      af.u[2] = cvt_pk_bf16(wb[j].x, wb[j].y);
      af.u[3] = cvt_pk_bf16(wb[j].z, wb[j].w);
      {
        f32x4 d = __builtin_amdgcn_mfma_f32_16x16x32_bf16(
            af.v, bx0, f32x4{0.f, 0.f, 0.f, 0.f}, 0, 0, 0);
        sacc[0] += d;
        u32x2 pk; pk.x = cvt_pk_bf16(d[0], d[1]); pk.y = cvt_pk_bf16(d[2], d[3]);
        *(u32x2*)(olds + ((ii << 5) + ccol) * 144 + (odl << 1)) = pk;
      }
      {
        f32x4 d = __builtin_amdgcn_mfma_f32_16x16x32_bf16(
            af.v, bx1, f32x4{0.f, 0.f, 0.f, 0.f}, 0, 0, 0);
        sacc[1] += d;
        u32x2 pk; pk.x = cvt_pk_bf16(d[0], d[1]); pk.y = cvt_pk_bf16(d[2], d[3]);
        *(u32x2*)(olds + ((ii << 5) + ccol + 16) * 144 + (odl << 1)) = pk;
      }
    }
  };

  f32x4 wa0[4], wb0[4], wa1[4], wb1[4];
  STAGE(0);
  ISSUE(0, 0, wa0, wb0);
  __syncthreads();

  for (int p = 0; p < 4; ++p) {
    const int i0 = (ib << 5) + (p << 3);
    ISSUE(p, 1, wa1, wb1);
    CONSUME(0, wa0, wb0);
    if (p < 3) ISSUE(p + 1, 0, wa0, wb0);
    CONSUME(1, wa1, wb1);
    __syncthreads();                 // olds complete; xlds fully consumed
    if (p < 3) STAGE(p + 1);         // overlaps U write-out (disjoint LDS)
    // Cooperative write-out: thread t covers 16B of u[b][i0+r][ob*64+od16*8..+8];
    // 8 consecutive threads = 128B contiguous -> full 64B lines -> NT-safe.
    {
      const int b    = tid >> 3;
      const int od16 = tid & 7;
#pragma unroll
      for (int r = 0; r < 8; ++r) {
        const u32x4 v = *(const u32x4*)(olds + ((r << 5) + b) * 144 + (od16 << 4));
        const size_t goff = (((size_t)(b * NI + i0 + r)) << 11) + (ob << 6) + (od16 << 3);
        __builtin_nontemporal_store(v, (u32x4*)(U + goff));
      }
    }
    __syncthreads();                 // write-out read done; xlds(p+1) visible
  }

  // per-i-block partial sums: part[ib][b][od] (wave-exclusive slice)
#pragma unroll
  for (int bt = 0; bt < 2; ++bt) {
    const int b  = ccol + (bt << 4);
    const int od = (ob << 6) + odl;
    float* pp = part + (((size_t)((ib << 5) + b)) << 11) + od;
    float4 t; t.x = sacc[bt][0]; t.y = sacc[bt][1];
    t.z = sacc[bt][2]; t.w = sacc[bt][3];
    *(float4*)pp = t;
  }
}

// Reduce partials over 64 chunks -> s[b,o,:], squash -> vout[b][o][d].
// wave <-> (b,o). 2048 waves = 512 blocks. scale: 1/64 for iter 1 (uniform c), else 1.
__global__ __launch_bounds__(256) void k_reduce(
    const float* __restrict__ part, float* __restrict__ vout, float scale) {
  const int tid  = threadIdx.x;
  const int lane = tid & 63;
  const int wid  = (blockIdx.x << 2) + (tid >> 6);
  const int o = wid & 63, b = wid >> 6;
  const int d = lane & 31, h = lane >> 5;
  float s = 0.f;
  for (int c = h; c < 64; c += 2)
    s += part[(((size_t)((c << 5) + b)) << 11) + (o << 5) + d];
  s += __shfl_xor(s, 32);
  s *= scale;
  float p = s * s;
#pragma unroll
  for (int off = 1; off < 32; off <<= 1) p += __shfl_xor(p, off);
  const float v = (p > 0.f) ? s * sqrtf(p) / (1.f + p) : 0.f;
  if (h == 0) vout[(((b << 6) + o) << 5) + d] = v;
}

// Routing pass: per (b,i): logits[o] = sum_d u*(v1[+v2]); softmax over o (64 lanes);
// partial s accumulation in registers; per-block LDS combine -> part[chunk][b][od].
// block <-> (b, chunk of 32 i); 4 waves x 8 i each. lane <-> o.
__global__ __launch_bounds__(256) void k_route(
    const unsigned short* __restrict__ U, const float* __restrict__ V1,
    const float* __restrict__ V2, float* __restrict__ part) {
  __shared__ float red[4][ODIM];   // 32 KiB
  const int tid   = threadIdx.x;
  const int lane  = tid & 63;
  const int w     = tid >> 6;
  const int b     = blockIdx.x >> 6;
  const int chunk = blockIdx.x & 63;
  const int o     = lane;

  // v (or v1+v2) for this lane's o: 32 regs, reused across all i
  float vs[32];
  {
    const float* vp = V1 + (((b << 6) + o) << 5);
#pragma unroll
    for (int j = 0; j < 8; ++j) {
      const float4 t = *(const float4*)(vp + (j << 2));
      vs[4*j+0] = t.x; vs[4*j+1] = t.y; vs[4*j+2] = t.z; vs[4*j+3] = t.w;
    }
    if (V2 != nullptr) {
      const float* vq = V2 + (((b << 6) + o) << 5);
#pragma unroll
      for (int j = 0; j < 8; ++j) {
        const float4 t = *(const float4*)(vq + (j << 2));
        vs[4*j+0] += t.x; vs[4*j+1] += t.y; vs[4*j+2] += t.z; vs[4*j+3] += t.w;
      }
    }
  }

  float pacc[32];
#pragma unroll
  for (int d = 0; d < 32; ++d) pacc[d] = 0.f;

  const int i0 = (chunk << 5) + (w << 3);
  const unsigned short* ub = U + (((size_t)b * NI) << 11);

  u32x4 q0, q1, q2, q3;   // prefetched 64B u-row slice for this lane's o
  {
    const u32x4* p = (const u32x4*)(ub + (((size_t)i0) << 11) + (o << 5));
    q0 = __builtin_nontemporal_load(p);
    q1 = __builtin_nontemporal_load(p + 1);
    q2 = __builtin_nontemporal_load(p + 2);
    q3 = __builtin_nontemporal_load(p + 3);
  }
  for (int ii = 0; ii < 8; ++ii) {
    const u32x4 c0 = q0, c1 = q1, c2 = q2, c3 = q3;
    if (ii < 7) {
      const u32x4* p = (const u32x4*)(ub + (((size_t)(i0 + ii + 1)) << 11) + (o << 5));
      q0 = __builtin_nontemporal_load(p);
      q1 = __builtin_nontemporal_load(p + 1);
      q2 = __builtin_nontemporal_load(p + 2);
      q3 = __builtin_nontemporal_load(p + 3);
    }
    float uf[32];
    uf[ 0]=bflo(c0.x); uf[ 1]=bfhi(c0.x); uf[ 2]=bflo(c0.y); uf[ 3]=bfhi(c0.y);
    uf[ 4]=bflo(c0.z); uf[ 5]=bfhi(c0.z); uf[ 6]=bflo(c0.w); uf[ 7]=bfhi(c0.w);
    uf[ 8]=bflo(c1.x); uf[ 9]=bfhi(c1.x); uf[10]=bflo(c1.y); uf[11]=bfhi(c1.y);
    uf[12]=bflo(c1.z); uf[13]=bfhi(c1.z); uf[14]=bflo(c1.w); uf[15]=bfhi(c1.w);
    uf[16]=bflo(c2.x); uf[17]=bfhi(c2.x); uf[18]=bflo(c2.y); uf[19]=bfhi(c2.y);
    uf[20]=bflo(c2.z); uf[21]=bfhi(c2.z); uf[22]=bflo(c2.w); uf[23]=bfhi(c2.w);
    uf[24]=bflo(c3.x); uf[25]=bfhi(c3.x); uf[26]=bflo(c3.y); uf[27]=bfhi(c3.y);
    uf[28]=bflo(c3.z); uf[29]=bfhi(c3.z); uf[30]=bflo(c3.w); uf[31]=bfhi(c3.w);

    float dotA = 0.f, dotB = 0.f;
#pragma unroll
    for (int d = 0; d < 16; ++d) {
      dotA = fmaf(uf[d], vs[d], dotA);
      dotB = fmaf(uf[d + 16], vs[d + 16], dotB);
    }
    const float dot = dotA + dotB;
    float m = dot;
#pragma unroll
    for (int off = 1; off < 64; off <<= 1) m = fmaxf(m, __shfl_xor(m, off));
    const float e = __expf(dot - m);
    float Z = e;
#pragma unroll
    for (int off = 1; off < 64; off <<= 1) Z += __shfl_xor(Z, off);
    const float c = e / Z;
#pragma unroll
    for (int d = 0; d < 32; ++d) pacc[d] = fmaf(c, uf[d], pacc[d]);
  }

#pragma unroll
  for (int j = 0; j < 8; ++j) {
    float4 t; t.x = pacc[4*j]; t.y = pacc[4*j+1]; t.z = pacc[4*j+2]; t.w = pacc[4*j+3];
    *(float4*)&red[w][(o << 5) + (j << 2)] = t;
  }
  __syncthreads();
  float* pout = part + (((size_t)((chunk << 5) + b)) << 11);
  for (int t = tid; t < ODIM; t += 256)
    pout[t] = red[0][t] + red[1][t] + red[2][t] + red[3][t];
}

extern "C" void kernel_launch(void* const* d_in, const int* in_sizes, int n_in,
                              void* d_out, int out_size, void* d_ws, size_t ws_size,
                              hipStream_t stream) {
  const float* X = (const float*)d_in[0];   // [32][2048][32]
  const float* W = (const float*)d_in[1];   // [64][2048][32][32]
  float* out = (float*)d_out;               // [32][64][32]
  char* ws = (char*)d_ws;

  // ws layout: u_hat bf16 256MiB | part fp32 16MiB | v1 | v2   (~272.5 MiB; ws=2GiB)
  unsigned short* U = (unsigned short*)ws;
  float* part = (float*)(ws + ((size_t)268435456));
  float* v1   = (float*)(ws + ((size_t)268435456 + 16777216));
  float* v2   = v1 + 65536;

  // iter 1: u_hat + uniform-c partial sums fused
  k1_uhat<<<2048, 256, 0, stream>>>(W, X, U, part);
  k_reduce<<<512, 256, 0, stream>>>(part, v1, 1.f / 64.f);
  // iter 2: logits = u.v1
  k_route<<<2048, 256, 0, stream>>>(U, v1, nullptr, part);
  k_reduce<<<512, 256, 0, stream>>>(part, v2, 1.f);
  // iter 3: logits = u.v1 + u.v2 = u.(v1+v2)
  k_route<<<2048, 256, 0, stream>>>(U, v1, v2, part);
  k_reduce<<<512, 256, 0, stream>>>(part, out, 1.f);
}

// Round 10
// 328.075 us; speedup vs baseline: 1.5988x; 1.2567x over previous
//
#include <hip/hip_runtime.h>

// Capsule routing: B=32, N_IN=2048, IN_DIM=32, N_OUT=64, OUT_DIM=32, 3 iterations.
#define NI   2048
#define NO   64
#define DD   32
#define ODIM 2048   // NO*DD, the fused (o,d) axis

typedef short bf16x8 __attribute__((ext_vector_type(8)));
typedef float f32x4  __attribute__((ext_vector_type(4)));
typedef unsigned int u32x2 __attribute__((ext_vector_type(2)));
typedef unsigned int u32x4 __attribute__((ext_vector_type(4)));

__device__ __forceinline__ unsigned int cvt_pk_bf16(float lo, float hi) {
  unsigned int r;
  asm("v_cvt_pk_bf16_f32 %0, %1, %2" : "=v"(r) : "v"(lo), "v"(hi));
  return r;
}
__device__ __forceinline__ float bflo(unsigned int u) { return __uint_as_float(u << 16); }
__device__ __forceinline__ float bfhi(unsigned int u) { return __uint_as_float(u & 0xffff0000u); }

union BFPack { unsigned int u[4]; bf16x8 v; };

// K1: u_hat[b][i][od] (bf16) = sum_k W[o,i,d,k]*x[b,i,k], via MFMA 16x16x32 bf16.
// Byte-identical to R8's passing kernel EXCEPT the U store is now a plain
// (cached) store instead of NT: stores are full-line, so no RMW risk, and
// letting U populate L2/L3 (U = 256MiB = L3 size) feeds the route passes.
// R9's 4-i-phase restructure raced on replay (passed validation, failed
// re-validation) -> reverted; k1 sync structure is frozen at R8's.
__global__ __launch_bounds__(256) void k1_uhat(
    const float* __restrict__ W, const float* __restrict__ X,
    unsigned short* __restrict__ U, float* __restrict__ part) {
  __shared__ __attribute__((aligned(16))) char olds[8 * 32 * 144];        // 36,864 B
  __shared__ __attribute__((aligned(16))) unsigned short xlds[8][32][32]; // 16,384 B
  const int tid   = threadIdx.x;
  const int lane  = tid & 63;
  const int w     = tid >> 6;
  const int ob    = blockIdx.x & 31;   // 64-od block
  const int ib    = blockIdx.x >> 5;   // i-block of 32
  const int odq   = (ob << 2) + w;     // 16-od strip
  const int o     = odq >> 1;          // output capsule
  const int db    = (odq & 1) << 4;    // d base within o
  const int row16 = lane & 15;         // A row within 16
  const int kg    = lane >> 4;         // k-group
  const int k0    = kg << 3;           // k offset (8 contiguous)
  const int crow  = kg << 2;           // C/D row base [m89 verified]
  const int ccol  = lane & 15;         // C/D col
  const int odl   = (w << 4) + crow;   // od within 64-od block
  const int sb    = tid >> 3;          // stage: b (0..31)
  const int sii   = tid & 7;           // stage: i within phase (0..7)
  const int xslot = (kg ^ (ccol & 3)) << 3;  // swizzled k-slot for consume reads

  f32x4 sacc[2];
  sacc[0] = f32x4{0.f, 0.f, 0.f, 0.f};
  sacc[1] = f32x4{0.f, 0.f, 0.f, 0.f};

  const float* wbase = W + (((size_t)o * NI) << 10) + ((db + row16) << 5) + k0;

  // Stage X[all b][phase 8 i][all k] -> xlds bf16. One (b,i) row per thread:
  // 8 coalesced float4 loads, cvt, 4 swizzled b128 LDS writes.
  auto STAGE = [&](int p) {
    const int i = (ib << 5) + (p << 3) + sii;
    const float4* xp = (const float4*)(X + (((size_t)(sb * NI + i)) << 5));
    float4 xv[8];
#pragma unroll
    for (int j = 0; j < 8; ++j) xv[j] = xp[j];
#pragma unroll
    for (int j = 0; j < 4; ++j) {
      u32x4 pk;
      pk.x = cvt_pk_bf16(xv[2*j].x,   xv[2*j].y);
      pk.y = cvt_pk_bf16(xv[2*j].z,   xv[2*j].w);
      pk.z = cvt_pk_bf16(xv[2*j+1].x, xv[2*j+1].y);
      pk.w = cvt_pk_bf16(xv[2*j+1].z, xv[2*j+1].w);
      *(u32x4*)&xlds[sii][sb][(j ^ (sb & 3)) << 3] = pk;
    }
  };

  // Issue W NT loads for a 4-i half-batch; pin the issue point.
  auto ISSUE = [&](int p, int h, f32x4* wa, f32x4* wb) {
    const int ia = (ib << 5) + (p << 3) + (h << 2);
#pragma unroll
    for (int j = 0; j < 4; ++j) {
      const f32x4* wp = (const f32x4*)(wbase + ((size_t)(ia + j) << 10));
      wa[j] = __builtin_nontemporal_load(wp);
      wb[j] = __builtin_nontemporal_load(wp + 1);
    }
    __builtin_amdgcn_sched_barrier(0);
  };

  // Consume a staged half-batch: A from W regs, B from xlds, 2 MFMA -> olds.
  auto CONSUME = [&](int h, const f32x4* wa, const f32x4* wb) {
#pragma unroll
    for (int j = 0; j < 4; ++j) {
      const int ii = (h << 2) + j;
      bf16x8 bx0 = *(const bf16x8*)&xlds[ii][ccol][xslot];
      bf16x8 bx1 = *(const bf16x8*)&xlds[ii][ccol + 16][xslot];
      BFPack af;
      af.u[0] = cvt_pk_bf16(wa[j].x, wa[j].y);
      af.u[1] = cvt_pk_bf16(wa[j].z, wa[j].w);
      af.u[2] = cvt_pk_bf16(wb[j].x, wb[j].y);
      af.u[3] = cvt_pk_bf16(wb[j].z, wb[j].w);
      {
        f32x4 d = __builtin_amdgcn_mfma_f32_16x16x32_bf16(
            af.v, bx0, f32x4{0.f, 0.f, 0.f, 0.f}, 0, 0, 0);
        sacc[0] += d;
        u32x2 pk; pk.x = cvt_pk_bf16(d[0], d[1]); pk.y = cvt_pk_bf16(d[2], d[3]);
        *(u32x2*)(olds + ((ii << 5) + ccol) * 144 + (odl << 1)) = pk;
      }
      {
        f32x4 d = __builtin_amdgcn_mfma_f32_16x16x32_bf16(
            af.v, bx1, f32x4{0.f, 0.f, 0.f, 0.f}, 0, 0, 0);
        sacc[1] += d;
        u32x2 pk; pk.x = cvt_pk_bf16(d[0], d[1]); pk.y = cvt_pk_bf16(d[2], d[3]);
        *(u32x2*)(olds + ((ii << 5) + ccol + 16) * 144 + (odl << 1)) = pk;
      }
    }
  };

  f32x4 wa0[4], wb0[4], wa1[4], wb1[4];
  STAGE(0);
  ISSUE(0, 0, wa0, wb0);
  __syncthreads();

  for (int p = 0; p < 4; ++p) {
    const int i0 = (ib << 5) + (p << 3);
    ISSUE(p, 1, wa1, wb1);
    CONSUME(0, wa0, wb0);
    if (p < 3) ISSUE(p + 1, 0, wa0, wb0);
    CONSUME(1, wa1, wb1);
    __syncthreads();                 // olds complete; xlds fully consumed
    if (p < 3) STAGE(p + 1);         // overlaps U write-out (disjoint LDS)
    // Cooperative write-out: thread t covers 16B of u[b][i0+r][ob*64+od16*8..+8];
    // 8 consecutive threads = 128B contiguous -> full 64B lines. Cached store:
    // populates L2/L3 for the route passes (U = 256MiB = L3 capacity).
    {
      const int b    = tid >> 3;
      const int od16 = tid & 7;
#pragma unroll
      for (int r = 0; r < 8; ++r) {
        const u32x4 v = *(const u32x4*)(olds + ((r << 5) + b) * 144 + (od16 << 4));
        const size_t goff = (((size_t)(b * NI + i0 + r)) << 11) + (ob << 6) + (od16 << 3);
        *(u32x4*)(U + goff) = v;
      }
    }
    __syncthreads();                 // write-out read done; xlds(p+1) visible
  }

  // per-i-block partial sums: part[ib][b][od] (wave-exclusive slice)
#pragma unroll
  for (int bt = 0; bt < 2; ++bt) {
    const int b  = ccol + (bt << 4);
    const int od = (ob << 6) + odl;
    float* pp = part + (((size_t)((ib << 5) + b)) << 11) + od;
    float4 t; t.x = sacc[bt][0]; t.y = sacc[bt][1];
    t.z = sacc[bt][2]; t.w = sacc[bt][3];
    *(float4*)pp = t;
  }
}

// Reduce partials over 64 chunks -> s[b,o,:], squash -> vout[b][o][d].
// wave <-> (b,o). 2048 waves = 512 blocks. scale: 1/64 for iter 1 (uniform c), else 1.
__global__ __launch_bounds__(256) void k_reduce(
    const float* __restrict__ part, float* __restrict__ vout, float scale) {
  const int tid  = threadIdx.x;
  const int lane = tid & 63;
  const int wid  = (blockIdx.x << 2) + (tid >> 6);
  const int o = wid & 63, b = wid >> 6;
  const int d = lane & 31, h = lane >> 5;
  float s = 0.f;
  for (int c = h; c < 64; c += 2)
    s += part[(((size_t)((c << 5) + b)) << 11) + (o << 5) + d];
  s += __shfl_xor(s, 32);
  s *= scale;
  float p = s * s;
#pragma unroll
  for (int off = 1; off < 32; off <<= 1) p += __shfl_xor(p, off);
  const float v = (p > 0.f) ? s * sqrtf(p) / (1.f + p) : 0.f;
  if (h == 0) vout[(((b << 6) + o) << 5) + d] = v;
}

// Routing pass: per (b,i): logits[o] = sum_d u*(v1[+v2]); softmax over o (64 lanes);
// partial s accumulation in registers; per-block LDS combine -> part[chunk][b][od].
// block <-> (b, chunk of 32 i); 4 waves x 8 i each. lane <-> o.
// U loads are now CACHED (not NT): iter-2 pulls U through L2/L3, iter-3 re-hits.
__global__ __launch_bounds__(256) void k_route(
    const unsigned short* __restrict__ U, const float* __restrict__ V1,
    const float* __restrict__ V2, float* __restrict__ part) {
  __shared__ float red[4][ODIM];   // 32 KiB
  const int tid   = threadIdx.x;
  const int lane  = tid & 63;
  const int w     = tid >> 6;
  const int b     = blockIdx.x >> 6;
  const int chunk = blockIdx.x & 63;
  const int o     = lane;

  // v (or v1+v2) for this lane's o: 32 regs, reused across all i
  float vs[32];
  {
    const float* vp = V1 + (((b << 6) + o) << 5);
#pragma unroll
    for (int j = 0; j < 8; ++j) {
      const float4 t = *(const float4*)(vp + (j << 2));
      vs[4*j+0] = t.x; vs[4*j+1] = t.y; vs[4*j+2] = t.z; vs[4*j+3] = t.w;
    }
    if (V2 != nullptr) {
      const float* vq = V2 + (((b << 6) + o) << 5);
#pragma unroll
      for (int j = 0; j < 8; ++j) {
        const float4 t = *(const float4*)(vq + (j << 2));
        vs[4*j+0] += t.x; vs[4*j+1] += t.y; vs[4*j+2] += t.z; vs[4*j+3] += t.w;
      }
    }
  }

  float pacc[32];
#pragma unroll
  for (int d = 0; d < 32; ++d) pacc[d] = 0.f;

  const int i0 = (chunk << 5) + (w << 3);
  const unsigned short* ub = U + (((size_t)b * NI) << 11);

  u32x4 q0, q1, q2, q3;   // prefetched 64B u-row slice for this lane's o
  {
    const u32x4* p = (const u32x4*)(ub + (((size_t)i0) << 11) + (o << 5));
    q0 = p[0]; q1 = p[1]; q2 = p[2]; q3 = p[3];
  }
  for (int ii = 0; ii < 8; ++ii) {
    const u32x4 c0 = q0, c1 = q1, c2 = q2, c3 = q3;
    if (ii < 7) {
      const u32x4* p = (const u32x4*)(ub + (((size_t)(i0 + ii + 1)) << 11) + (o << 5));
      q0 = p[0]; q1 = p[1]; q2 = p[2]; q3 = p[3];
    }
    float uf[32];
    uf[ 0]=bflo(c0.x); uf[ 1]=bfhi(c0.x); uf[ 2]=bflo(c0.y); uf[ 3]=bfhi(c0.y);
    uf[ 4]=bflo(c0.z); uf[ 5]=bfhi(c0.z); uf[ 6]=bflo(c0.w); uf[ 7]=bfhi(c0.w);
    uf[ 8]=bflo(c1.x); uf[ 9]=bfhi(c1.x); uf[10]=bflo(c1.y); uf[11]=bfhi(c1.y);
    uf[12]=bflo(c1.z); uf[13]=bfhi(c1.z); uf[14]=bflo(c1.w); uf[15]=bfhi(c1.w);
    uf[16]=bflo(c2.x); uf[17]=bfhi(c2.x); uf[18]=bflo(c2.y); uf[19]=bfhi(c2.y);
    uf[20]=bflo(c2.z); uf[21]=bfhi(c2.z); uf[22]=bflo(c2.w); uf[23]=bfhi(c2.w);
    uf[24]=bflo(c3.x); uf[25]=bfhi(c3.x); uf[26]=bflo(c3.y); uf[27]=bfhi(c3.y);
    uf[28]=bflo(c3.z); uf[29]=bfhi(c3.z); uf[30]=bflo(c3.w); uf[31]=bfhi(c3.w);

    float dotA = 0.f, dotB = 0.f;
#pragma unroll
    for (int d = 0; d < 16; ++d) {
      dotA = fmaf(uf[d], vs[d], dotA);
      dotB = fmaf(uf[d + 16], vs[d + 16], dotB);
    }
    const float dot = dotA + dotB;
    float m = dot;
#pragma unroll
    for (int off = 1; off < 64; off <<= 1) m = fmaxf(m, __shfl_xor(m, off));
    const float e = __expf(dot - m);
    float Z = e;
#pragma unroll
    for (int off = 1; off < 64; off <<= 1) Z += __shfl_xor(Z, off);
    const float c = e / Z;
#pragma unroll
    for (int d = 0; d < 32; ++d) pacc[d] = fmaf(c, uf[d], pacc[d]);
  }

#pragma unroll
  for (int j = 0; j < 8; ++j) {
    float4 t; t.x = pacc[4*j]; t.y = pacc[4*j+1]; t.z = pacc[4*j+2]; t.w = pacc[4*j+3];
    *(float4*)&red[w][(o << 5) + (j << 2)] = t;
  }
  __syncthreads();
  float* pout = part + (((size_t)((chunk << 5) + b)) << 11);
  for (int t = tid; t < ODIM; t += 256)
    pout[t] = red[0][t] + red[1][t] + red[2][t] + red[3][t];
}

extern "C" void kernel_launch(void* const* d_in, const int* in_sizes, int n_in,
                              void* d_out, int out_size, void* d_ws, size_t ws_size,
                              hipStream_t stream) {
  const float* X = (const float*)d_in[0];   // [32][2048][32]
  const float* W = (const float*)d_in[1];   // [64][2048][32][32]
  float* out = (float*)d_out;               // [32][64][32]
  char* ws = (char*)d_ws;

  // ws layout: u_hat bf16 256MiB | part fp32 16MiB | v1 | v2   (~272.5 MiB; ws=2GiB)
  unsigned short* U = (unsigned short*)ws;
  float* part = (float*)(ws + ((size_t)268435456));
  float* v1   = (float*)(ws + ((size_t)268435456 + 16777216));
  float* v2   = v1 + 65536;

  // iter 1: u_hat + uniform-c partial sums fused
  k1_uhat<<<2048, 256, 0, stream>>>(W, X, U, part);
  k_reduce<<<512, 256, 0, stream>>>(part, v1, 1.f / 64.f);
  // iter 2: logits = u.v1
  k_route<<<2048, 256, 0, stream>>>(U, v1, nullptr, part);
  k_reduce<<<512, 256, 0, stream>>>(part, v2, 1.f);
  // iter 3: logits = u.v1 + u.v2 = u.(v1+v2)
  k_route<<<2048, 256, 0, stream>>>(U, v1, v2, part);
  k_reduce<<<512, 256, 0, stream>>>(part, out, 1.f);
}

// Round 11
// 327.618 us; speedup vs baseline: 1.6010x; 1.0014x over previous
//
#include <hip/hip_runtime.h>

// Capsule routing: B=32, N_IN=2048, IN_DIM=32, N_OUT=64, OUT_DIM=32, 3 iterations.
#define NI   2048
#define NO   64
#define DD   32
#define ODIM 2048   // NO*DD, the fused (o,d) axis

typedef short bf16x8 __attribute__((ext_vector_type(8)));
typedef float f32x4  __attribute__((ext_vector_type(4)));
typedef unsigned int u32x2 __attribute__((ext_vector_type(2)));
typedef unsigned int u32x4 __attribute__((ext_vector_type(4)));

__device__ __forceinline__ unsigned int cvt_pk_bf16(float lo, float hi) {
  unsigned int r;
  asm("v_cvt_pk_bf16_f32 %0, %1, %2" : "=v"(r) : "v"(lo), "v"(hi));
  return r;
}
__device__ __forceinline__ float bflo(unsigned int u) { return __uint_as_float(u << 16); }
__device__ __forceinline__ float bfhi(unsigned int u) { return __uint_as_float(u & 0xffff0000u); }

union BFPack { unsigned int u[4]; bf16x8 v; };

// LDS-only barrier: waits ds ops (lgkmcnt) but does NOT drain vmcnt, so U
// stores and W prefetches stay in flight across phases. __syncthreads would
// emit s_waitcnt vmcnt(0) before s_barrier (the ~20% drain stall, guide §5).
// All cross-wave deps in k1 flow through LDS -> lgkmcnt(0)+barrier suffices.
// sched_barrier(0) fences prevent hipcc reordering mem ops across it (rule 18).
__device__ __forceinline__ void barrier_lds_only() {
  asm volatile("s_waitcnt lgkmcnt(0)" ::: "memory");
  __builtin_amdgcn_sched_barrier(0);
  __builtin_amdgcn_s_barrier();
  __builtin_amdgcn_sched_barrier(0);
}

// K1: u_hat[b][i][od] (bf16) = sum_k W[o,i,d,k]*x[b,i,k], via MFMA 16x16x32 bf16.
// R11 = R10 (passing, 328us) with ONE change: both in-loop barriers (and the
// prologue barrier) use barrier_lds_only() instead of __syncthreads(). Phase
// structure, work split, and barrier COUNT are byte-identical to R8/R10 (R9's
// restructure raced; this is not a restructure).
__global__ __launch_bounds__(256) void k1_uhat(
    const float* __restrict__ W, const float* __restrict__ X,
    unsigned short* __restrict__ U, float* __restrict__ part) {
  __shared__ __attribute__((aligned(16))) char olds[8 * 32 * 144];        // 36,864 B
  __shared__ __attribute__((aligned(16))) unsigned short xlds[8][32][32]; // 16,384 B
  const int tid   = threadIdx.x;
  const int lane  = tid & 63;
  const int w     = tid >> 6;
  const int ob    = blockIdx.x & 31;   // 64-od block
  const int ib    = blockIdx.x >> 5;   // i-block of 32
  const int odq   = (ob << 2) + w;     // 16-od strip
  const int o     = odq >> 1;          // output capsule
  const int db    = (odq & 1) << 4;    // d base within o
  const int row16 = lane & 15;         // A row within 16
  const int kg    = lane >> 4;         // k-group
  const int k0    = kg << 3;           // k offset (8 contiguous)
  const int crow  = kg << 2;           // C/D row base [m89 verified]
  const int ccol  = lane & 15;         // C/D col
  const int odl   = (w << 4) + crow;   // od within 64-od block
  const int sb    = tid >> 3;          // stage: b (0..31)
  const int sii   = tid & 7;           // stage: i within phase (0..7)
  const int xslot = (kg ^ (ccol & 3)) << 3;  // swizzled k-slot for consume reads

  f32x4 sacc[2];
  sacc[0] = f32x4{0.f, 0.f, 0.f, 0.f};
  sacc[1] = f32x4{0.f, 0.f, 0.f, 0.f};

  const float* wbase = W + (((size_t)o * NI) << 10) + ((db + row16) << 5) + k0;

  // Stage X[all b][phase 8 i][all k] -> xlds bf16. One (b,i) row per thread:
  // 8 coalesced float4 loads, cvt, 4 swizzled b128 LDS writes.
  auto STAGE = [&](int p) {
    const int i = (ib << 5) + (p << 3) + sii;
    const float4* xp = (const float4*)(X + (((size_t)(sb * NI + i)) << 5));
    float4 xv[8];
#pragma unroll
    for (int j = 0; j < 8; ++j) xv[j] = xp[j];
#pragma unroll
    for (int j = 0; j < 4; ++j) {
      u32x4 pk;
      pk.x = cvt_pk_bf16(xv[2*j].x,   xv[2*j].y);
      pk.y = cvt_pk_bf16(xv[2*j].z,   xv[2*j].w);
      pk.z = cvt_pk_bf16(xv[2*j+1].x, xv[2*j+1].y);
      pk.w = cvt_pk_bf16(xv[2*j+1].z, xv[2*j+1].w);
      *(u32x4*)&xlds[sii][sb][(j ^ (sb & 3)) << 3] = pk;
    }
  };

  // Issue W NT loads for a 4-i half-batch; pin the issue point.
  auto ISSUE = [&](int p, int h, f32x4* wa, f32x4* wb) {
    const int ia = (ib << 5) + (p << 3) + (h << 2);
#pragma unroll
    for (int j = 0; j < 4; ++j) {
      const f32x4* wp = (const f32x4*)(wbase + ((size_t)(ia + j) << 10));
      wa[j] = __builtin_nontemporal_load(wp);
      wb[j] = __builtin_nontemporal_load(wp + 1);
    }
    __builtin_amdgcn_sched_barrier(0);
  };

  // Consume a staged half-batch: A from W regs, B from xlds, 2 MFMA -> olds.
  auto CONSUME = [&](int h, const f32x4* wa, const f32x4* wb) {
#pragma unroll
    for (int j = 0; j < 4; ++j) {
      const int ii = (h << 2) + j;
      bf16x8 bx0 = *(const bf16x8*)&xlds[ii][ccol][xslot];
      bf16x8 bx1 = *(const bf16x8*)&xlds[ii][ccol + 16][xslot];
      BFPack af;
      af.u[0] = cvt_pk_bf16(wa[j].x, wa[j].y);
      af.u[1] = cvt_pk_bf16(wa[j].z, wa[j].w);
      af.u[2] = cvt_pk_bf16(wb[j].x, wb[j].y);
      af.u[3] = cvt_pk_bf16(wb[j].z, wb[j].w);
      {
        f32x4 d = __builtin_amdgcn_mfma_f32_16x16x32_bf16(
            af.v, bx0, f32x4{0.f, 0.f, 0.f, 0.f}, 0, 0, 0);
        sacc[0] += d;
        u32x2 pk; pk.x = cvt_pk_bf16(d[0], d[1]); pk.y = cvt_pk_bf16(d[2], d[3]);
        *(u32x2*)(olds + ((ii << 5) + ccol) * 144 + (odl << 1)) = pk;
      }
      {
        f32x4 d = __builtin_amdgcn_mfma_f32_16x16x32_bf16(
            af.v, bx1, f32x4{0.f, 0.f, 0.f, 0.f}, 0, 0, 0);
        sacc[1] += d;
        u32x2 pk; pk.x = cvt_pk_bf16(d[0], d[1]); pk.y = cvt_pk_bf16(d[2], d[3]);
        *(u32x2*)(olds + ((ii << 5) + ccol + 16) * 144 + (odl << 1)) = pk;
      }
    }
  };

  f32x4 wa0[4], wb0[4], wa1[4], wb1[4];
  STAGE(0);
  ISSUE(0, 0, wa0, wb0);
  barrier_lds_only();

  for (int p = 0; p < 4; ++p) {
    const int i0 = (ib << 5) + (p << 3);
    ISSUE(p, 1, wa1, wb1);
    CONSUME(0, wa0, wb0);
    if (p < 3) ISSUE(p + 1, 0, wa0, wb0);
    CONSUME(1, wa1, wb1);
    barrier_lds_only();              // olds complete; xlds fully consumed
    if (p < 3) STAGE(p + 1);         // overlaps U write-out (disjoint LDS)
    // Cooperative write-out: thread t covers 16B of u[b][i0+r][ob*64+od16*8..+8];
    // 8 consecutive threads = 128B contiguous -> full 64B lines. Cached store:
    // populates L2/L3 for the route passes (U = 256MiB = L3 capacity).
    {
      const int b    = tid >> 3;
      const int od16 = tid & 7;
#pragma unroll
      for (int r = 0; r < 8; ++r) {
        const u32x4 v = *(const u32x4*)(olds + ((r << 5) + b) * 144 + (od16 << 4));
        const size_t goff = (((size_t)(b * NI + i0 + r)) << 11) + (ob << 6) + (od16 << 3);
        *(u32x4*)(U + goff) = v;
      }
    }
    barrier_lds_only();              // write-out read done; xlds(p+1) visible
  }

  // per-i-block partial sums: part[ib][b][od] (wave-exclusive slice)
#pragma unroll
  for (int bt = 0; bt < 2; ++bt) {
    const int b  = ccol + (bt << 4);
    const int od = (ob << 6) + odl;
    float* pp = part + (((size_t)((ib << 5) + b)) << 11) + od;
    float4 t; t.x = sacc[bt][0]; t.y = sacc[bt][1];
    t.z = sacc[bt][2]; t.w = sacc[bt][3];
    *(float4*)pp = t;
  }
}

// Reduce partials over 64 chunks -> s[b,o,:], squash -> vout[b][o][d].
// wave <-> (b,o). 2048 waves = 512 blocks. scale: 1/64 for iter 1 (uniform c), else 1.
__global__ __launch_bounds__(256) void k_reduce(
    const float* __restrict__ part, float* __restrict__ vout, float scale) {
  const int tid  = threadIdx.x;
  const int lane = tid & 63;
  const int wid  = (blockIdx.x << 2) + (tid >> 6);
  const int o = wid & 63, b = wid >> 6;
  const int d = lane & 31, h = lane >> 5;
  float s = 0.f;
  for (int c = h; c < 64; c += 2)
    s += part[(((size_t)((c << 5) + b)) << 11) + (o << 5) + d];
  s += __shfl_xor(s, 32);
  s *= scale;
  float p = s * s;
#pragma unroll
  for (int off = 1; off < 32; off <<= 1) p += __shfl_xor(p, off);
  const float v = (p > 0.f) ? s * sqrtf(p) / (1.f + p) : 0.f;
  if (h == 0) vout[(((b << 6) + o) << 5) + d] = v;
}

// Routing pass: per (b,i): logits[o] = sum_d u*(v1[+v2]); softmax over o (64 lanes);
// partial s accumulation in registers; per-block LDS combine -> part[chunk][b][od].
// block <-> (b, chunk of 32 i); 4 waves x 8 i each. lane <-> o.
// U loads CACHED: iter-2 pulls U through L2/L3, iter-3 re-hits.
__global__ __launch_bounds__(256) void k_route(
    const unsigned short* __restrict__ U, const float* __restrict__ V1,
    const float* __restrict__ V2, float* __restrict__ part) {
  __shared__ float red[4][ODIM];   // 32 KiB
  const int tid   = threadIdx.x;
  const int lane  = tid & 63;
  const int w     = tid >> 6;
  const int b     = blockIdx.x >> 6;
  const int chunk = blockIdx.x & 63;
  const int o     = lane;

  // v (or v1+v2) for this lane's o: 32 regs, reused across all i
  float vs[32];
  {
    const float* vp = V1 + (((b << 6) + o) << 5);
#pragma unroll
    for (int j = 0; j < 8; ++j) {
      const float4 t = *(const float4*)(vp + (j << 2));
      vs[4*j+0] = t.x; vs[4*j+1] = t.y; vs[4*j+2] = t.z; vs[4*j+3] = t.w;
    }
    if (V2 != nullptr) {
      const float* vq = V2 + (((b << 6) + o) << 5);
#pragma unroll
      for (int j = 0; j < 8; ++j) {
        const float4 t = *(const float4*)(vq + (j << 2));
        vs[4*j+0] += t.x; vs[4*j+1] += t.y; vs[4*j+2] += t.z; vs[4*j+3] += t.w;
      }
    }
  }

  float pacc[32];
#pragma unroll
  for (int d = 0; d < 32; ++d) pacc[d] = 0.f;

  const int i0 = (chunk << 5) + (w << 3);
  const unsigned short* ub = U + (((size_t)b * NI) << 11);

  u32x4 q0, q1, q2, q3;   // prefetched 64B u-row slice for this lane's o
  {
    const u32x4* p = (const u32x4*)(ub + (((size_t)i0) << 11) + (o << 5));
    q0 = p[0]; q1 = p[1]; q2 = p[2]; q3 = p[3];
  }
  for (int ii = 0; ii < 8; ++ii) {
    const u32x4 c0 = q0, c1 = q1, c2 = q2, c3 = q3;
    if (ii < 7) {
      const u32x4* p = (const u32x4*)(ub + (((size_t)(i0 + ii + 1)) << 11) + (o << 5));
      q0 = p[0]; q1 = p[1]; q2 = p[2]; q3 = p[3];
    }
    float uf[32];
    uf[ 0]=bflo(c0.x); uf[ 1]=bfhi(c0.x); uf[ 2]=bflo(c0.y); uf[ 3]=bfhi(c0.y);
    uf[ 4]=bflo(c0.z); uf[ 5]=bfhi(c0.z); uf[ 6]=bflo(c0.w); uf[ 7]=bfhi(c0.w);
    uf[ 8]=bflo(c1.x); uf[ 9]=bfhi(c1.x); uf[10]=bflo(c1.y); uf[11]=bfhi(c1.y);
    uf[12]=bflo(c1.z); uf[13]=bfhi(c1.z); uf[14]=bflo(c1.w); uf[15]=bfhi(c1.w);
    uf[16]=bflo(c2.x); uf[17]=bfhi(c2.x); uf[18]=bflo(c2.y); uf[19]=bfhi(c2.y);
    uf[20]=bflo(c2.z); uf[21]=bfhi(c2.z); uf[22]=bflo(c2.w); uf[23]=bfhi(c2.w);
    uf[24]=bflo(c3.x); uf[25]=bfhi(c3.x); uf[26]=bflo(c3.y); uf[27]=bfhi(c3.y);
    uf[28]=bflo(c3.z); uf[29]=bfhi(c3.z); uf[30]=bflo(c3.w); uf[31]=bfhi(c3.w);

    float dotA = 0.f, dotB = 0.f;
#pragma unroll
    for (int d = 0; d < 16; ++d) {
      dotA = fmaf(uf[d], vs[d], dotA);
      dotB = fmaf(uf[d + 16], vs[d + 16], dotB);
    }
    const float dot = dotA + dotB;
    float m = dot;
#pragma unroll
    for (int off = 1; off < 64; off <<= 1) m = fmaxf(m, __shfl_xor(m, off));
    const float e = __expf(dot - m);
    float Z = e;
#pragma unroll
    for (int off = 1; off < 64; off <<= 1) Z += __shfl_xor(Z, off);
    const float c = e / Z;
#pragma unroll
    for (int d = 0; d < 32; ++d) pacc[d] = fmaf(c, uf[d], pacc[d]);
  }

#pragma unroll
  for (int j = 0; j < 8; ++j) {
    float4 t; t.x = pacc[4*j]; t.y = pacc[4*j+1]; t.z = pacc[4*j+2]; t.w = pacc[4*j+3];
    *(float4*)&red[w][(o << 5) + (j << 2)] = t;
  }
  __syncthreads();
  float* pout = part + (((size_t)((chunk << 5) + b)) << 11);
  for (int t = tid; t < ODIM; t += 256)
    pout[t] = red[0][t] + red[1][t] + red[2][t] + red[3][t];
}

extern "C" void kernel_launch(void* const* d_in, const int* in_sizes, int n_in,
                              void* d_out, int out_size, void* d_ws, size_t ws_size,
                              hipStream_t stream) {
  const float* X = (const float*)d_in[0];   // [32][2048][32]
  const float* W = (const float*)d_in[1];   // [64][2048][32][32]
  float* out = (float*)d_out;               // [32][64][32]
  char* ws = (char*)d_ws;

  // ws layout: u_hat bf16 256MiB | part fp32 16MiB | v1 | v2   (~272.5 MiB; ws=2GiB)
  unsigned short* U = (unsigned short*)ws;
  float* part = (float*)(ws + ((size_t)268435456));
  float* v1   = (float*)(ws + ((size_t)268435456 + 16777216));
  float* v2   = v1 + 65536;

  // iter 1: u_hat + uniform-c partial sums fused
  k1_uhat<<<2048, 256, 0, stream>>>(W, X, U, part);
  k_reduce<<<512, 256, 0, stream>>>(part, v1, 1.f / 64.f);
  // iter 2: logits = u.v1
  k_route<<<2048, 256, 0, stream>>>(U, v1, nullptr, part);
  k_reduce<<<512, 256, 0, stream>>>(part, v2, 1.f);
  // iter 3: logits = u.v1 + u.v2 = u.(v1+v2)
  k_route<<<2048, 256, 0, stream>>>(U, v1, v2, part);
  k_reduce<<<512, 256, 0, stream>>>(part, out, 1.f);
}